// Round 5
// baseline (1221.230 us; speedup 1.0000x reference)
//
#include <hip/hip_runtime.h>

#define KCW 1024   // num codewords
#define DIM 64     // embedding dim

// ---------------------------------------------------------------------------
// Pre-kernel: cnorm[k] = sum_d codebook[k][d]^2   (1024 floats into d_ws)
// ---------------------------------------------------------------------------
__global__ void __launch_bounds__(256) vq_cnorm_kernel(const float* __restrict__ cb,
                                                       float* __restrict__ cnorm) {
    int k = blockIdx.x * blockDim.x + threadIdx.x;
    if (k < KCW) {
        const float4* c4 = (const float4*)(cb + (size_t)k * DIM);
        float s0 = 0.f, s1 = 0.f, s2 = 0.f, s3 = 0.f;
#pragma unroll
        for (int j = 0; j < DIM / 4; j += 4) {
            float4 a = c4[j + 0];
            float4 b = c4[j + 1];
            float4 c = c4[j + 2];
            float4 d = c4[j + 3];
            s0 += a.x * a.x + a.y * a.y + a.z * a.z + a.w * a.w;
            s1 += b.x * b.x + b.y * b.y + b.z * b.z + b.w * b.w;
            s2 += c.x * c.x + c.y * c.y + c.z * c.z + c.w * c.w;
            s3 += d.x * d.x + d.y * d.y + d.z * d.z + d.w * d.w;
        }
        cnorm[k] = (s0 + s1) + (s2 + s3);
    }
}

// SGPR vector type: one s_load_dwordx16 result (16 floats, SGPR 16-tuple)
typedef __attribute__((ext_vector_type(16))) float sfvec16;

// Issue two s_load_dwordx16 (32 floats) — no wait. Address is wave-uniform.
__device__ __forceinline__ void sload32(sfvec16& a, sfvec16& b,
                                        const float* base, int boff) {
    asm volatile("s_load_dwordx16 %0, %2, %3\n\t"
                 "s_load_dwordx16 %1, %2, %4"
                 : "=s"(a), "=s"(b)
                 : "s"(base), "s"(boff), "s"(boff + 64));
}

__device__ __forceinline__ void sload1(float& c, const float* base, int boff) {
    asm volatile("s_load_dword %0, %1, %2" : "=s"(c) : "s"(base), "s"(boff));
}

// Wait with data-dependence ties: consumers of the tied values cannot be
// scheduled above the waitcnt.
#define WAIT2(a, b)    asm volatile("s_waitcnt lgkmcnt(0)" : "+s"(a), "+s"(b));
#define WAIT3(a, b, c) asm volatile("s_waitcnt lgkmcnt(0)" : "+s"(a), "+s"(b), "+s"(c));

// 4 fmaf into one accumulator, codeword element from SGPR (v_fma_f32 takes
// exactly one SGPR source). Same association as the passing R1 kernel.
#define FMA4S(acc, xv, sv, o)             \
    acc = fmaf(xv.x, sv[(o) + 0], acc);   \
    acc = fmaf(xv.y, sv[(o) + 1], acc);   \
    acc = fmaf(xv.z, sv[(o) + 2], acc);   \
    acc = fmaf(xv.w, sv[(o) + 3], acc);

// Pin x row in VGPRs (R3->R4: stops the compiler re-loading x in-loop).
#define PIN4(a, b, c, d)                                                   \
    asm volatile("" : "+v"(a.x), "+v"(a.y), "+v"(a.z), "+v"(a.w),          \
                      "+v"(b.x), "+v"(b.y), "+v"(b.z), "+v"(b.w),          \
                      "+v"(c.x), "+v"(c.y), "+v"(c.z), "+v"(c.w),          \
                      "+v"(d.x), "+v"(d.y), "+v"(d.z), "+v"(d.w));

// ---------------------------------------------------------------------------
// Main kernel: one thread per row. x pinned in 64 VGPRs. Codeword streamed
// through the SCALAR pipe (s_load_dwordx16 -> SGPRs -> v_fma SGPR operand):
// R4 was LDS-issue-bound on 16 broadcast ds_read_b128/codeword/wave (~655us);
// scalar broadcast costs zero LDS/VMEM/VALU. Half-codeword software pipeline
// (SMEM is out-of-order -> only lgkmcnt(0) is safe; wait->issue->consume).
// ---------------------------------------------------------------------------
__global__ void __launch_bounds__(256, 2) vq_main_kernel(const float* __restrict__ x,
                                                         const float* __restrict__ cb,
                                                         const float* __restrict__ cnorm,
                                                         float* __restrict__ out_discrete,
                                                         float* __restrict__ out_quant) {
    __shared__ int sIdx[256];

    const int tid = threadIdx.x;
    const int row = blockIdx.x * 256 + tid;

    // x row in 16 named float4 (64 VGPRs), pinned live across the k-loop.
    const float4* xr = (const float4*)(x + (size_t)row * DIM);
    float4 x0 = xr[0], x1 = xr[1], x2 = xr[2], x3 = xr[3];
    float4 x4 = xr[4], x5 = xr[5], x6 = xr[6], x7 = xr[7];
    float4 x8 = xr[8], x9 = xr[9], x10 = xr[10], x11 = xr[11];
    float4 x12 = xr[12], x13 = xr[13], x14 = xr[14], x15 = xr[15];
    PIN4(x0, x1, x2, x3)
    PIN4(x4, x5, x6, x7)
    PIN4(x8, x9, x10, x11)
    PIN4(x12, x13, x14, x15)

    float best = 3.4e38f;
    int bestIdx = 0;

    // preload half0 of codeword 0 + cnorm[0]
    sfvec16 curA, curB;
    float cnk;
    sload32(curA, curB, cb, 0);
    sload1(cnk, cnorm, 0);

#pragma unroll 2
    for (int k = 0; k < KCW; ++k) {
        const int kn = (k < KCW - 1) ? (k + 1) : (KCW - 1);  // clamp: no OOB prefetch

        WAIT3(curA, curB, cnk)  // half0 of k ready (issued last iteration)

        sfvec16 hC, hD;
        sload32(hC, hD, cb, k * 256 + 128);  // issue half1 of k

        // consume half0: x0..x7  (a0..a3 pattern identical to R1)
        float a0 = 0.f, a1 = 0.f, a2 = 0.f, a3 = 0.f;
        FMA4S(a0, x0, curA, 0)
        FMA4S(a1, x1, curA, 4)
        FMA4S(a2, x2, curA, 8)
        FMA4S(a3, x3, curA, 12)
        FMA4S(a0, x4, curB, 0)
        FMA4S(a1, x5, curB, 4)
        FMA4S(a2, x6, curB, 8)
        FMA4S(a3, x7, curB, 12)

        WAIT2(hC, hD)  // half1 of k ready

        sfvec16 nxtA, nxtB;
        float cnk_next;
        sload32(nxtA, nxtB, cb, kn * 256);  // issue half0 of k+1
        sload1(cnk_next, cnorm, kn * 4);

        // consume half1: x8..x15
        FMA4S(a0, x8, hC, 0)
        FMA4S(a1, x9, hC, 4)
        FMA4S(a2, x10, hC, 8)
        FMA4S(a3, x11, hC, 12)
        FMA4S(a0, x12, hD, 0)
        FMA4S(a1, x13, hD, 4)
        FMA4S(a2, x14, hD, 8)
        FMA4S(a3, x15, hD, 12)

        float dot = (a0 + a1) + (a2 + a3);
        float score = fmaf(-2.f, dot, cnk);
        // strict < keeps earliest index on ties, matching np.argmin
        if (score < best) {
            best = score;
            bestIdx = k;
        }

        curA = nxtA;
        curB = nxtB;
        cnk = cnk_next;
    }

    sIdx[tid] = bestIdx;
    __syncthreads();

    // ---- quantized: rows [blockIdx*256, +256), 256*16 float4, coalesced ----
    {
        float4* q4 = (float4*)(out_quant + (size_t)blockIdx.x * 256 * DIM);
#pragma unroll
        for (int i = 0; i < 16; ++i) {
            int chunk = i * 256 + tid;
            int rl = chunk >> 4;   // local row (16 float4 per row)
            int j = chunk & 15;    // float4 index within row
            int idx = sIdx[rl];
            const float4* src = (const float4*)cb + (idx << 4);
            q4[chunk] = src[j];
        }
    }

    // ---- one-hot: 256 rows x 1024 floats, fully coalesced float4 stores ----
    {
        float4* o4 = (float4*)(out_discrete + (size_t)blockIdx.x * 256 * KCW);
        const int col = tid * 4;
        for (int it = 0; it < 256; ++it) {
            int idx = sIdx[it];  // block-uniform per iteration
            float4 v;
            v.x = (col + 0 == idx) ? 1.f : 0.f;
            v.y = (col + 1 == idx) ? 1.f : 0.f;
            v.z = (col + 2 == idx) ? 1.f : 0.f;
            v.w = (col + 3 == idx) ? 1.f : 0.f;
            o4[(size_t)it * 256 + tid] = v;
        }
    }
}

// ---------------------------------------------------------------------------
extern "C" void kernel_launch(void* const* d_in, const int* in_sizes, int n_in,
                              void* d_out, int out_size, void* d_ws, size_t ws_size,
                              hipStream_t stream) {
    const float* x = (const float*)d_in[0];
    const float* cb = (const float*)d_in[1];
    float* cnorm = (float*)d_ws;  // 1024 floats of scratch

    const int n = in_sizes[0];        // 8388608
    const int rows = n / DIM;         // 131072

    float* out_discrete = (float*)d_out;
    float* out_quant = (float*)d_out + (size_t)rows * KCW;

    vq_cnorm_kernel<<<(KCW + 255) / 256, 256, 0, stream>>>(cb, cnorm);
    vq_main_kernel<<<rows / 256, 256, 0, stream>>>(x, cb, cnorm, out_discrete, out_quant);
}

// Round 8
// 917.027 us; speedup vs baseline: 1.3317x; 1.3317x over previous
//
#include <hip/hip_runtime.h>

#define KCW 1024     // num codewords
#define DIM 64       // embedding dim
#define ROWS_BLK 256 // rows per block (2 stripes)
#define STRIPE 128   // rows per stripe
#define CWTILE 128   // codewords per LDS phase

// ---------------------------------------------------------------------------
// Pre-kernel: cnorm[k] = sum_d codebook[k][d]^2   (1024 floats into d_ws)
// ---------------------------------------------------------------------------
__global__ void __launch_bounds__(256) vq_cnorm_kernel(const float* __restrict__ cb,
                                                       float* __restrict__ cnorm) {
    int k = blockIdx.x * blockDim.x + threadIdx.x;
    if (k < KCW) {
        const float4* c4 = (const float4*)(cb + (size_t)k * DIM);
        float s0 = 0.f, s1 = 0.f, s2 = 0.f, s3 = 0.f;
#pragma unroll
        for (int j = 0; j < DIM / 4; j += 4) {
            float4 a = c4[j + 0];
            float4 b = c4[j + 1];
            float4 c = c4[j + 2];
            float4 d = c4[j + 3];
            s0 += a.x * a.x + a.y * a.y + a.z * a.z + a.w * a.w;
            s1 += b.x * b.x + b.y * b.y + b.z * b.z + b.w * b.w;
            s2 += c.x * c.x + c.y * c.y + c.z * c.z + c.w * c.w;
            s3 += d.x * d.x + d.y * d.y + d.z * d.z + d.w * d.w;
        }
        cnorm[k] = (s0 + s1) + (s2 + s3);
    }
}

// sequential x,y,z,w chain (closest feasible to R1's verified association)
#define DOT4ACC(acc, av, bv)                                               \
    acc = fmaf((av).w, (bv).w,                                             \
          fmaf((av).z, (bv).z,                                             \
          fmaf((av).y, (bv).y,                                             \
          fmaf((av).x, (bv).x, (acc)))));

#define ROWFMA(r)                                                          \
    DOT4ACC(q##r##a.x, a##r, b0) DOT4ACC(q##r##a.y, a##r, b1)              \
    DOT4ACC(q##r##a.z, a##r, b2) DOT4ACC(q##r##a.w, a##r, b3)              \
    DOT4ACC(q##r##b.x, a##r, b4) DOT4ACC(q##r##b.y, a##r, b5)              \
    DOT4ACC(q##r##b.z, a##r, b6) DOT4ACC(q##r##b.w, a##r, b7)

#define UPROW(r, X)                                                        \
    { float s_ = fmaf(-2.f, q##r##X, cn);                                  \
      if (s_ < best##r) { best##r = s_; bidx##r = cwv; } }

#define UPCOL(c, X)                                                        \
    { const float cn = sCn[cnb + 8 * (c)];                                 \
      const int cwv = cwbase + 8 * (c);                                    \
      UPROW(0, X) UPROW(1, X) UPROW(2, X) UPROW(3, X)                      \
      UPROW(4, X) UPROW(5, X) UPROW(6, X) UPROW(7, X) }

#define MERGEPUT(r)                                                        \
    { int rl = 64 * wr + ty + 8 * (r);                                     \
      sMs[rl * 16 + slot] = best##r; sMi[rl * 16 + slot] = bidx##r; }

// ---------------------------------------------------------------------------
// Register-tiled distance GEMM with streaming argmin.
// LDS = 66,560 B <= 67,584 B (largest PROVEN-launchable static LDS, R4).
// R6 (138,752) and R7 (70,144) produced stub-identical zero output =>
// launch failure; the per-WG LDS cliff is in (67584, 70144].
// No padding: XOR swizzle slot(row,ch)=row*16+(ch^2*(row&7)) makes both the
// A reads (vary ty) and B reads (vary tx) <=2-way conflicted (free, m136).
// All accumulators / best / bidx are NAMED scalars (R2: arrays -> scratch).
// ---------------------------------------------------------------------------
__global__ void __launch_bounds__(256, 2) vq_main_kernel(const float* __restrict__ x,
                                                         const float* __restrict__ cb,
                                                         const float* __restrict__ cnorm,
                                                         float* __restrict__ out_discrete,
                                                         float* __restrict__ out_quant) {
    __shared__ float4 sX[STRIPE * 16];   // 32768 B (merge arrays alias this)
    __shared__ float4 sC[CWTILE * 16];   // 32768 B
    __shared__ float sCn[CWTILE];        // 512 B
    __shared__ int sFinal[STRIPE];       // 512 B                 total 66560

    float* sMs = (float*)sX;                 // 128 rows x 16 slots scores
    int* sMi = ((int*)sX) + STRIPE * 16;     // 128 rows x 16 slots indices

    const int tid = threadIdx.x;
    const int wave = tid >> 6;
    const int lane = tid & 63;
    const int wr = wave >> 1;   // row-group 0..1  (64 rows each)
    const int wc = wave & 1;    // cw-group 0..1   (64 cws each)
    const int ty = lane >> 3;   // 0..7
    const int tx = lane & 7;    // 0..7

    const int row0 = blockIdx.x * ROWS_BLK;
    const float4* xg = (const float4*)x;
    const float4* cbg = (const float4*)cb;
    float4* od4 = (float4*)out_discrete;
    float4* oq4 = (float4*)out_quant;

    const int cnb = 64 * wc + tx;          // first cw of this thread in tile
    const int abase = (64 * wr + ty) * 16; // f4 base of first micro-row
    const int bbase = (64 * wc + tx) * 16; // f4 base of first micro-col
    const int ty2 = ty << 1;
    const int tx2 = tx << 1;
    const int slot = wc * 8 + tx;

    for (int s = 0; s < ROWS_BLK / STRIPE; ++s) {
        const int grow0 = row0 + s * STRIPE;

        __syncthreads();  // (A) prior stripe's sFinal/sMs readers done

        // ---- stage x-stripe: 128 rows x 16 f4, swizzled ----
#pragma unroll
        for (int i = 0; i < 8; ++i) {
            int e = i * 256 + tid;
            int r = e >> 4, ch = e & 15;
            sX[r * 16 + (ch ^ ((r & 7) << 1))] = xg[(size_t)(grow0 + r) * 16 + ch];
        }

        float best0 = 3.4e38f, best1 = 3.4e38f, best2 = 3.4e38f, best3 = 3.4e38f;
        float best4 = 3.4e38f, best5 = 3.4e38f, best6 = 3.4e38f, best7 = 3.4e38f;
        int bidx0 = 0, bidx1 = 0, bidx2 = 0, bidx3 = 0;
        int bidx4 = 0, bidx5 = 0, bidx6 = 0, bidx7 = 0;

        for (int p = 0; p < KCW / CWTILE; ++p) {
            __syncthreads();  // (B) prior phase's sC/sCn readers done

            // ---- stage cw tile: 128 cw x 16 f4, swizzled ----
#pragma unroll
            for (int i = 0; i < 8; ++i) {
                int e = i * 256 + tid;
                int c = e >> 4, ch = e & 15;
                sC[c * 16 + (ch ^ ((c & 7) << 1))] =
                    cbg[(size_t)(p * CWTILE + c) * 16 + ch];
            }
            if (tid < CWTILE) sCn[tid] = cnorm[p * CWTILE + tid];
            __syncthreads();  // (C) tile staged

            float4 q0a = {0.f, 0.f, 0.f, 0.f}, q0b = {0.f, 0.f, 0.f, 0.f};
            float4 q1a = {0.f, 0.f, 0.f, 0.f}, q1b = {0.f, 0.f, 0.f, 0.f};
            float4 q2a = {0.f, 0.f, 0.f, 0.f}, q2b = {0.f, 0.f, 0.f, 0.f};
            float4 q3a = {0.f, 0.f, 0.f, 0.f}, q3b = {0.f, 0.f, 0.f, 0.f};
            float4 q4a = {0.f, 0.f, 0.f, 0.f}, q4b = {0.f, 0.f, 0.f, 0.f};
            float4 q5a = {0.f, 0.f, 0.f, 0.f}, q5b = {0.f, 0.f, 0.f, 0.f};
            float4 q6a = {0.f, 0.f, 0.f, 0.f}, q6b = {0.f, 0.f, 0.f, 0.f};
            float4 q7a = {0.f, 0.f, 0.f, 0.f}, q7b = {0.f, 0.f, 0.f, 0.f};

#pragma unroll
            for (int k4 = 0; k4 < 16; ++k4) {
                const int ka = k4 ^ ty2;  // swizzled k-slot for A rows
                const int kb = k4 ^ tx2;  // swizzled k-slot for B cols
                const float4 a0 = sX[abase + ka + 0 * 128];
                const float4 a1 = sX[abase + ka + 1 * 128];
                const float4 a2 = sX[abase + ka + 2 * 128];
                const float4 a3 = sX[abase + ka + 3 * 128];
                const float4 a4 = sX[abase + ka + 4 * 128];
                const float4 a5 = sX[abase + ka + 5 * 128];
                const float4 a6 = sX[abase + ka + 6 * 128];
                const float4 a7 = sX[abase + ka + 7 * 128];
                const float4 b0 = sC[bbase + kb + 0 * 128];
                const float4 b1 = sC[bbase + kb + 1 * 128];
                const float4 b2 = sC[bbase + kb + 2 * 128];
                const float4 b3 = sC[bbase + kb + 3 * 128];
                const float4 b4 = sC[bbase + kb + 4 * 128];
                const float4 b5 = sC[bbase + kb + 5 * 128];
                const float4 b6 = sC[bbase + kb + 6 * 128];
                const float4 b7 = sC[bbase + kb + 7 * 128];
                ROWFMA(0) ROWFMA(1) ROWFMA(2) ROWFMA(3)
                ROWFMA(4) ROWFMA(5) ROWFMA(6) ROWFMA(7)
            }

            // ---- scores + running argmin (cw ascending -> strict < keeps
            //      earliest index, matching np.argmin) ----
            const int cwbase = p * CWTILE + 64 * wc + tx;
            UPCOL(0, a.x) UPCOL(1, a.y) UPCOL(2, a.z) UPCOL(3, a.w)
            UPCOL(4, b.x) UPCOL(5, b.y) UPCOL(6, b.z) UPCOL(7, b.w)
        }

        __syncthreads();  // (D) compute done -> safe to alias sX with merge

        MERGEPUT(0) MERGEPUT(1) MERGEPUT(2) MERGEPUT(3)
        MERGEPUT(4) MERGEPUT(5) MERGEPUT(6) MERGEPUT(7)
        __syncthreads();  // (E)

        if (tid < STRIPE) {
            float bs = sMs[tid * 16];
            int bi = sMi[tid * 16];
#pragma unroll
            for (int j = 1; j < 16; ++j) {
                float sj = sMs[tid * 16 + j];
                int ij = sMi[tid * 16 + j];
                if (sj < bs || (sj == bs && ij < bi)) { bs = sj; bi = ij; }
            }
            sFinal[tid] = bi;
        }
        __syncthreads();  // (F)

        // ---- epilogue: one-hot (128 rows x 256 f4) + quantized (128 x 16 f4) ----
        {
            size_t obase = (size_t)grow0 * (KCW / 4);
            const int col = tid * 4;
            for (int it = 0; it < STRIPE; ++it) {
                int idx = sFinal[it];  // block-uniform per iteration
                float4 v;
                v.x = (col + 0 == idx) ? 1.f : 0.f;
                v.y = (col + 1 == idx) ? 1.f : 0.f;
                v.z = (col + 2 == idx) ? 1.f : 0.f;
                v.w = (col + 3 == idx) ? 1.f : 0.f;
                od4[obase + (size_t)it * 256 + tid] = v;
            }
            size_t qbase = (size_t)grow0 * 16;
#pragma unroll
            for (int it = 0; it < 8; ++it) {
                int cnk = it * 256 + tid;
                int r = cnk >> 4;
                int ch = cnk & 15;
                oq4[qbase + cnk] = cbg[(size_t)sFinal[r] * 16 + ch];
            }
        }
    }
}

// ---------------------------------------------------------------------------
extern "C" void kernel_launch(void* const* d_in, const int* in_sizes, int n_in,
                              void* d_out, int out_size, void* d_ws, size_t ws_size,
                              hipStream_t stream) {
    const float* x = (const float*)d_in[0];
    const float* cb = (const float*)d_in[1];
    float* cnorm = (float*)d_ws;  // 1024 floats of scratch

    const int n = in_sizes[0];    // 8388608
    const int rows = n / DIM;     // 131072

    float* out_discrete = (float*)d_out;
    float* out_quant = (float*)d_out + (size_t)rows * KCW;

    vq_cnorm_kernel<<<(KCW + 255) / 256, 256, 0, stream>>>(cb, cnorm);
    vq_main_kernel<<<rows / ROWS_BLK, 256, 0, stream>>>(x, cb, cnorm, out_discrete, out_quant);
}

// Round 10
// 814.791 us; speedup vs baseline: 1.4988x; 1.1255x over previous
//
#include <hip/hip_runtime.h>

#define KCW 1024     // num codewords
#define DIM 64       // embedding dim
#define ROWS_BLK 256 // rows per block (2 stripes)
#define STRIPE 128   // rows per stripe
#define CWTILE 128   // codewords per LDS phase

typedef __attribute__((ext_vector_type(4))) float f32x4;

// ---------------------------------------------------------------------------
// Pre-kernel: cnorm[k] = sum_d codebook[k][d]^2   (1024 floats into d_ws)
// ---------------------------------------------------------------------------
__global__ void __launch_bounds__(256) vq_cnorm_kernel(const float* __restrict__ cb,
                                                       float* __restrict__ cnorm) {
    int k = blockIdx.x * blockDim.x + threadIdx.x;
    if (k < KCW) {
        const float4* c4 = (const float4*)(cb + (size_t)k * DIM);
        float s0 = 0.f, s1 = 0.f, s2 = 0.f, s3 = 0.f;
#pragma unroll
        for (int j = 0; j < DIM / 4; j += 4) {
            float4 a = c4[j + 0];
            float4 b = c4[j + 1];
            float4 c = c4[j + 2];
            float4 d = c4[j + 3];
            s0 += a.x * a.x + a.y * a.y + a.z * a.z + a.w * a.w;
            s1 += b.x * b.x + b.y * b.y + b.z * b.z + b.w * b.w;
            s2 += c.x * c.x + c.y * c.y + c.z * c.z + c.w * c.w;
            s3 += d.x * d.x + d.y * d.y + d.z * d.z + d.w * d.w;
        }
        cnorm[k] = (s0 + s1) + (s2 + s3);
    }
}

// sequential x,y,z,w chain — bit-identical association to R8 (passed)
#define DOT4ACC(acc, av, bv)                                               \
    acc = fmaf((av).w, (bv).w,                                             \
          fmaf((av).z, (bv).z,                                             \
          fmaf((av).y, (bv).y,                                             \
          fmaf((av).x, (bv).x, (acc)))));

// one micro-row n against all 8 col fragments of buffer P
// (param renamed r->n: R9's `r##P##r` pasted BOTH r's -> `0A0` octal error)
#define ROWF(P, n)                                                         \
    DOT4ACC(q##n##a.x, r##P##n, c##P##0) DOT4ACC(q##n##a.y, r##P##n, c##P##1) \
    DOT4ACC(q##n##a.z, r##P##n, c##P##2) DOT4ACC(q##n##a.w, r##P##n, c##P##3) \
    DOT4ACC(q##n##b.x, r##P##n, c##P##4) DOT4ACC(q##n##b.y, r##P##n, c##P##5) \
    DOT4ACC(q##n##b.z, r##P##n, c##P##6) DOT4ACC(q##n##b.w, r##P##n, c##P##7)

#define FMAB(P) ROWF(P, 0) ROWF(P, 1) ROWF(P, 2) ROWF(P, 3)                \
                ROWF(P, 4) ROWF(P, 5) ROWF(P, 6) ROWF(P, 7)

// load one k4-slice of operands (8 A-rows + 8 B-cols) into buffer P's regs
#define LOADOPS(P, k4v)                                                    \
    {   const int ka_ = (k4v) ^ ty2;                                       \
        const int kb_ = (k4v) ^ tx2;                                       \
        r##P##0 = sX[abase + ka_ + 0 * 128];                               \
        r##P##1 = sX[abase + ka_ + 1 * 128];                               \
        r##P##2 = sX[abase + ka_ + 2 * 128];                               \
        r##P##3 = sX[abase + ka_ + 3 * 128];                               \
        r##P##4 = sX[abase + ka_ + 4 * 128];                               \
        r##P##5 = sX[abase + ka_ + 5 * 128];                               \
        r##P##6 = sX[abase + ka_ + 6 * 128];                               \
        r##P##7 = sX[abase + ka_ + 7 * 128];                               \
        c##P##0 = sC[bbase + kb_ + 0 * 128];                               \
        c##P##1 = sC[bbase + kb_ + 1 * 128];                               \
        c##P##2 = sC[bbase + kb_ + 2 * 128];                               \
        c##P##3 = sC[bbase + kb_ + 3 * 128];                               \
        c##P##4 = sC[bbase + kb_ + 4 * 128];                               \
        c##P##5 = sC[bbase + kb_ + 5 * 128];                               \
        c##P##6 = sC[bbase + kb_ + 6 * 128];                               \
        c##P##7 = sC[bbase + kb_ + 7 * 128]; }

#define UPROW(n, X)                                                        \
    { float s_ = fmaf(-2.f, q##n##X, cn);                                  \
      if (s_ < best##n) { best##n = s_; bidx##n = cwv; } }

#define UPCOL(c, X)                                                        \
    { const float cn = sCn[cnb + 8 * (c)];                                 \
      const int cwv = cwbase + 8 * (c);                                    \
      UPROW(0, X) UPROW(1, X) UPROW(2, X) UPROW(3, X)                      \
      UPROW(4, X) UPROW(5, X) UPROW(6, X) UPROW(7, X) }

#define MERGEPUT(n)                                                        \
    { int rl = 64 * wr + ty + 8 * (n);                                     \
      sMs[rl * 16 + slot] = best##n; sMi[rl * 16 + slot] = bidx##n; }

// ---------------------------------------------------------------------------
// Register-tiled distance GEMM, streaming argmin, explicit k4 ping-pong:
// R8 stalled load-wait-FMA per k4 at VGPR=128 (VALUBusy 43%, no pipe
// saturated). Two operand buffers (32 f4 = 128 VGPR) + 64 acc ~ 200 VGPR
// under (256,2): k4's 512 FMA cycles hide k4+1's 16 ds_read_b128.
// LDS = 66,560 B (<= proven cliff; R7's 70,144 failed to launch).
// ---------------------------------------------------------------------------
__global__ void __launch_bounds__(256, 2) vq_main_kernel(const float* __restrict__ x,
                                                         const float* __restrict__ cb,
                                                         const float* __restrict__ cnorm,
                                                         float* __restrict__ out_discrete,
                                                         float* __restrict__ out_quant) {
    __shared__ float4 sX[STRIPE * 16];   // 32768 B (merge arrays alias this)
    __shared__ float4 sC[CWTILE * 16];   // 32768 B
    __shared__ float sCn[CWTILE];        // 512 B
    __shared__ int sFinal[STRIPE];       // 512 B                 total 66560

    float* sMs = (float*)sX;                 // 128 rows x 16 slots scores
    int* sMi = ((int*)sX) + STRIPE * 16;     // 128 rows x 16 slots indices

    const int tid = threadIdx.x;
    const int wave = tid >> 6;
    const int lane = tid & 63;
    const int wr = wave >> 1;   // row-group 0..1  (64 rows each)
    const int wc = wave & 1;    // cw-group 0..1   (64 cws each)
    const int ty = lane >> 3;   // 0..7
    const int tx = lane & 7;    // 0..7

    const int row0 = blockIdx.x * ROWS_BLK;
    const float4* xg = (const float4*)x;
    const float4* cbg = (const float4*)cb;
    float4* od4 = (float4*)out_discrete;
    float4* oq4 = (float4*)out_quant;

    const int cnb = 64 * wc + tx;          // first cw of this thread in tile
    const int abase = (64 * wr + ty) * 16; // f4 base of first micro-row
    const int bbase = (64 * wc + tx) * 16; // f4 base of first micro-col
    const int ty2 = ty << 1;
    const int tx2 = tx << 1;
    const int slot = wc * 8 + tx;

    for (int s = 0; s < ROWS_BLK / STRIPE; ++s) {
        const int grow0 = row0 + s * STRIPE;

        __syncthreads();  // (A) prior stripe's sFinal/sMs readers done

        // ---- stage x-stripe: 128 rows x 16 f4, swizzled ----
#pragma unroll
        for (int i = 0; i < 8; ++i) {
            int e = i * 256 + tid;
            int r = e >> 4, ch = e & 15;
            sX[r * 16 + (ch ^ ((r & 7) << 1))] = xg[(size_t)(grow0 + r) * 16 + ch];
        }

        float best0 = 3.4e38f, best1 = 3.4e38f, best2 = 3.4e38f, best3 = 3.4e38f;
        float best4 = 3.4e38f, best5 = 3.4e38f, best6 = 3.4e38f, best7 = 3.4e38f;
        int bidx0 = 0, bidx1 = 0, bidx2 = 0, bidx3 = 0;
        int bidx4 = 0, bidx5 = 0, bidx6 = 0, bidx7 = 0;

        for (int p = 0; p < KCW / CWTILE; ++p) {
            __syncthreads();  // (B) prior phase's sC/sCn readers done

            // ---- stage cw tile: 128 cw x 16 f4, swizzled ----
#pragma unroll
            for (int i = 0; i < 8; ++i) {
                int e = i * 256 + tid;
                int c = e >> 4, ch = e & 15;
                sC[c * 16 + (ch ^ ((c & 7) << 1))] =
                    cbg[(size_t)(p * CWTILE + c) * 16 + ch];
            }
            if (tid < CWTILE) sCn[tid] = cnorm[p * CWTILE + tid];
            __syncthreads();  // (C) tile staged

            float4 q0a = {0.f, 0.f, 0.f, 0.f}, q0b = {0.f, 0.f, 0.f, 0.f};
            float4 q1a = {0.f, 0.f, 0.f, 0.f}, q1b = {0.f, 0.f, 0.f, 0.f};
            float4 q2a = {0.f, 0.f, 0.f, 0.f}, q2b = {0.f, 0.f, 0.f, 0.f};
            float4 q3a = {0.f, 0.f, 0.f, 0.f}, q3b = {0.f, 0.f, 0.f, 0.f};
            float4 q4a = {0.f, 0.f, 0.f, 0.f}, q4b = {0.f, 0.f, 0.f, 0.f};
            float4 q5a = {0.f, 0.f, 0.f, 0.f}, q5b = {0.f, 0.f, 0.f, 0.f};
            float4 q6a = {0.f, 0.f, 0.f, 0.f}, q6b = {0.f, 0.f, 0.f, 0.f};
            float4 q7a = {0.f, 0.f, 0.f, 0.f}, q7b = {0.f, 0.f, 0.f, 0.f};

            // ping-pong operand buffers A/B (32 float4 = 128 VGPRs)
            float4 rA0, rA1, rA2, rA3, rA4, rA5, rA6, rA7;
            float4 cA0, cA1, cA2, cA3, cA4, cA5, cA6, cA7;
            float4 rB0, rB1, rB2, rB3, rB4, rB5, rB6, rB7;
            float4 cB0, cB1, cB2, cB3, cB4, cB5, cB6, cB7;

            LOADOPS(A, 0)
#pragma unroll
            for (int k4 = 0; k4 < 16; k4 += 2) {
                LOADOPS(B, k4 + 1)   // issue k4+1 loads before k4's FMAs
                FMAB(A)
                if (k4 + 2 < 16) LOADOPS(A, k4 + 2)
                FMAB(B)
            }

            // ---- scores + running argmin (cw ascending -> strict < keeps
            //      earliest index, matching np.argmin) ----
            const int cwbase = p * CWTILE + 64 * wc + tx;
            UPCOL(0, a.x) UPCOL(1, a.y) UPCOL(2, a.z) UPCOL(3, a.w)
            UPCOL(4, b.x) UPCOL(5, b.y) UPCOL(6, b.z) UPCOL(7, b.w)
        }

        __syncthreads();  // (D) compute done -> safe to alias sX with merge

        MERGEPUT(0) MERGEPUT(1) MERGEPUT(2) MERGEPUT(3)
        MERGEPUT(4) MERGEPUT(5) MERGEPUT(6) MERGEPUT(7)
        __syncthreads();  // (E)

        if (tid < STRIPE) {
            float bs = sMs[tid * 16];
            int bi = sMi[tid * 16];
#pragma unroll
            for (int j = 1; j < 16; ++j) {
                float sj = sMs[tid * 16 + j];
                int ij = sMi[tid * 16 + j];
                if (sj < bs || (sj == bs && ij < bi)) { bs = sj; bi = ij; }
            }
            sFinal[tid] = bi;
        }
        __syncthreads();  // (F)

        // ---- epilogue: nontemporal streaming stores (outputs never re-read;
        //      keep the 600 MB write stream out of L2) ----
        {
            size_t obase = (size_t)grow0 * (KCW / 4);
            const int col = tid * 4;
            for (int it = 0; it < STRIPE; ++it) {
                int idx = sFinal[it];  // block-uniform per iteration
                f32x4 v;
                v.x = (col + 0 == idx) ? 1.f : 0.f;
                v.y = (col + 1 == idx) ? 1.f : 0.f;
                v.z = (col + 2 == idx) ? 1.f : 0.f;
                v.w = (col + 3 == idx) ? 1.f : 0.f;
                __builtin_nontemporal_store(v, (f32x4*)&od4[obase + (size_t)it * 256 + tid]);
            }
            size_t qbase = (size_t)grow0 * 16;
#pragma unroll
            for (int it = 0; it < 8; ++it) {
                int cnk = it * 256 + tid;
                int r = cnk >> 4;
                int ch = cnk & 15;
                float4 qv = cbg[(size_t)sFinal[r] * 16 + ch];
                __builtin_nontemporal_store(*(f32x4*)&qv, (f32x4*)&oq4[qbase + cnk]);
            }
        }
    }
}

// ---------------------------------------------------------------------------
extern "C" void kernel_launch(void* const* d_in, const int* in_sizes, int n_in,
                              void* d_out, int out_size, void* d_ws, size_t ws_size,
                              hipStream_t stream) {
    const float* x = (const float*)d_in[0];
    const float* cb = (const float*)d_in[1];
    float* cnorm = (float*)d_ws;  // 1024 floats of scratch

    const int n = in_sizes[0];    // 8388608
    const int rows = n / DIM;     // 131072

    float* out_discrete = (float*)d_out;
    float* out_quant = (float*)d_out + (size_t)rows * KCW;

    vq_cnorm_kernel<<<(KCW + 255) / 256, 256, 0, stream>>>(cb, cnorm);
    vq_main_kernel<<<rows / ROWS_BLK, 256, 0, stream>>>(x, cb, cnorm, out_discrete, out_quant);
}